// Round 12
// baseline (166.303 us; speedup 1.0000x reference)
//
#include <hip/hip_runtime.h>
#include <stdint.h>

#define LOG2E 1.44269504088896340736f
#define QSCALE (0.125f * LOG2E)   // dim_head^-0.5 folded with log2(e) for exp2-domain softmax

typedef __bf16 bf16x8 __attribute__((ext_vector_type(8)));
typedef float floatx4 __attribute__((ext_vector_type(4)));

__device__ __forceinline__ unsigned short bfbits(float f) {
  __bf16 h = (__bf16)f;
  return __builtin_bit_cast(unsigned short, h);
}

__device__ __forceinline__ float fast_exp2(float x) {
#if __has_builtin(__builtin_amdgcn_exp2f)
  return __builtin_amdgcn_exp2f(x);
#else
  return exp2f(x);
#endif
}

__device__ __forceinline__ void gl2lds16(const void* g, void* l) {
  __builtin_amdgcn_global_load_lds((const __attribute__((address_space(1))) void*)g,
                                   (__attribute__((address_space(3))) void*)l, 16, 0, 0);
}

// ---------------- prep: transpose-cvt of Wq/Wkv/Wo only ----------------
__global__ __launch_bounds__(256)
void prep_kernel(const float* __restrict__ Wq, const float* __restrict__ Wkv,
                 const float* __restrict__ Wo,
                 unsigned short* __restrict__ WqT, unsigned short* __restrict__ WkvT,
                 unsigned short* __restrict__ WoT) {
  __shared__ float tile[32][33];
  int t = blockIdx.x;  // 0..1023
  int tid = threadIdx.x;
  const float* in; unsigned short* out; int N; int tb;
  if (t < 256)      { in = Wq;  out = WqT;  N = 512;  tb = t; }
  else if (t < 768) { in = Wkv; out = WkvT; N = 1024; tb = t - 256; }
  else              { in = Wo;  out = WoT;  N = 512;  tb = t - 768; }
  const int K = 512;
  int nbx = N / 32;
  int n0 = (tb % nbx) * 32, k0 = (tb / nbx) * 32;
  int tx = tid & 31, ty = tid >> 5;
#pragma unroll
  for (int r = ty; r < 32; r += 8)
    tile[r][tx] = in[(long)(k0 + r) * N + n0 + tx];
  __syncthreads();
#pragma unroll
  for (int r = ty; r < 32; r += 8)
    out[(long)(n0 + r) * K + k0 + tx] = bfbits(tile[tx][r]);
}

// ---------------- proj: fused Q/KV GEMMs, 128x128x64 tiles, LDS dbuf, fp32-A in-flight cvt ----------------
// BK 32->64: halves the barrier/vmcnt(0)-drain count (16->8) and doubles per-step MFMA (32) and
// the cold-A-load flight window (~600cyc vs ~900 HBM-cold latency). Same dbuf + __syncthreads
// structure (the only schedule class that has worked). 64KB LDS -> 2 blocks/CU; r10 showed
// occupancy is not proj's binding constraint. XOR-chunk swizzle = r1/r5 scheme (0 conflicts).
__global__ __launch_bounds__(256)
void proj_gemm(const float* __restrict__ Xf, const float* __restrict__ Cf,
               const unsigned short* __restrict__ WqT, const unsigned short* __restrict__ WkvT,
               unsigned short* __restrict__ Qb, unsigned short* __restrict__ Kb,
               unsigned short* __restrict__ Vt) {
  __shared__ unsigned short As[2][128 * 64];  // 16 KB each
  __shared__ unsigned short Bs[2][128 * 64];

  int idx0 = blockIdx.x;
  int idx = (idx0 & 7) * 96 + (idx0 >> 3);  // bijective XCD swizzle (768 % 8 == 0)
  const float* A; const unsigned short* Bt;
  long bm, bn; int role;
  if (idx < 256) { role = 0; A = Xf; Bt = WqT;  bn = (long)(idx & 3) * 128; bm = (long)(idx >> 2) * 128; }
  else { int j = idx - 256; role = 1; A = Cf; Bt = WkvT; bn = (long)(j & 7) * 128; bm = (long)(j >> 3) * 128; }

  const int tid = threadIdx.x;
  const int wave = tid >> 6;
  const int lane = tid & 63;
  const int l15 = lane & 15;
  const int q4 = lane >> 4;
  const int s7 = l15 & 7;
  const int wm = (wave & 1) * 64;
  const int wn = (wave >> 1) * 64;
  const int K = 512;

  // A reg-staging: thread = (row = tid>>1, half = tid&1); 32 fp32 -> 32 bf16 = 4 LDS chunks
  const int ars = tid >> 1, ahalf = tid & 1;
  const long aF = (bm + ars) * 512 + ahalf * 32;
  int awr[4];
#pragma unroll
  for (int w = 0; w < 4; ++w)
    awr[w] = ars * 64 + (((ahalf * 4 + w) ^ (ars & 7)) * 8);

  // B staging: 4 gl2lds chunks/thread, swizzled global source, linear LDS dest
  int boff[4], lds16b[4];
#pragma unroll
  for (int cc = 0; cc < 4; ++cc) {
    int c = cc * 256 + tid;
    int r = c >> 3, kc = c & 7;
    int gc = kc ^ (r & 7);
    boff[cc] = (int)(bn + r) * K + gc * 8;
    lds16b[cc] = c * 16;
  }
  // fragment reads: global chunk (ks*4+q4), stored at position ^ (row&7); row&7 == l15&7
  int csw[2];
#pragma unroll
  for (int ks = 0; ks < 2; ++ks) csw[ks] = ((ks * 4 + q4) ^ s7) * 8;
  int arow[4], brow[4];
#pragma unroll
  for (int i = 0; i < 4; ++i) {
    arow[i] = (wm + i * 16 + l15) * 64;
    brow[i] = (wn + i * 16 + l15) * 64;
  }

  floatx4 acc[4][4];
#pragma unroll
  for (int i = 0; i < 4; ++i)
#pragma unroll
    for (int j = 0; j < 4; ++j) { acc[i][j][0]=0.f; acc[i][j][1]=0.f; acc[i][j][2]=0.f; acc[i][j][3]=0.f; }

  float4 va[8];

#define PROJ_LOADA(KOFF)                                                   \
  {                                                                        \
    _Pragma("unroll")                                                      \
    for (int w = 0; w < 8; ++w)                                            \
      va[w] = *(const float4*)(A + aF + (KOFF) + w * 4);                   \
  }

#define PROJ_WRITEA(BUF)                                                   \
  {                                                                        \
    _Pragma("unroll")                                                      \
    for (int w = 0; w < 4; ++w) {                                          \
      uint4 pk;                                                            \
      pk.x = (unsigned)bfbits(va[2*w].x) | ((unsigned)bfbits(va[2*w].y) << 16);     \
      pk.y = (unsigned)bfbits(va[2*w].z) | ((unsigned)bfbits(va[2*w].w) << 16);     \
      pk.z = (unsigned)bfbits(va[2*w+1].x) | ((unsigned)bfbits(va[2*w+1].y) << 16); \
      pk.w = (unsigned)bfbits(va[2*w+1].z) | ((unsigned)bfbits(va[2*w+1].w) << 16); \
      *(uint4*)(As[(BUF)] + awr[w]) = pk;                                  \
    }                                                                      \
  }

#define PROJ_STAGEB(BUF, KOFF)                                             \
  {                                                                        \
    _Pragma("unroll")                                                      \
    for (int cc = 0; cc < 4; ++cc)                                         \
      gl2lds16(Bt + boff[cc] + (KOFF), (char*)Bs[(BUF)] + lds16b[cc]);     \
  }

#define PROJ_STEP(T, CUR, DO_STAGE)                                        \
  {                                                                        \
    if (DO_STAGE) { PROJ_LOADA(((T) + 1) * 64); PROJ_STAGEB((CUR) ^ 1, ((T) + 1) * 64); } \
    _Pragma("unroll")                                                      \
    for (int ks = 0; ks < 2; ++ks) {                                       \
      bf16x8 af[4], bfr[4];                                                \
      _Pragma("unroll")                                                    \
      for (int i = 0; i < 4; ++i) af[i] = *(const bf16x8*)(As[(CUR)] + arow[i] + csw[ks]); \
      _Pragma("unroll")                                                    \
      for (int j = 0; j < 4; ++j) bfr[j] = *(const bf16x8*)(Bs[(CUR)] + brow[j] + csw[ks]); \
      _Pragma("unroll")                                                    \
      for (int i = 0; i < 4; ++i)                                          \
        _Pragma("unroll")                                                  \
        for (int j = 0; j < 4; ++j)                                        \
          acc[i][j] = __builtin_amdgcn_mfma_f32_16x16x32_bf16(af[i], bfr[j], acc[i][j], 0, 0, 0); \
    }                                                                      \
    if (DO_STAGE) PROJ_WRITEA((CUR) ^ 1);                                  \
    if ((T) < 7) __syncthreads();                                          \
  }

  PROJ_LOADA(0);
  PROJ_STAGEB(0, 0);
  PROJ_WRITEA(0);
  __syncthreads();
  for (int tt = 0; tt < 4; ++tt) {
    PROJ_STEP(2 * tt, 0, true);
    PROJ_STEP(2 * tt + 1, 1, (tt < 3));
  }
#undef PROJ_STEP
#undef PROJ_STAGEB
#undef PROJ_WRITEA
#undef PROJ_LOADA

  const bool vrole = (role == 1) && (bn >= 512);
#pragma unroll
  for (int i = 0; i < 4; ++i) {
#pragma unroll
    for (int j = 0; j < 4; ++j) {
      long col = bn + wn + j * 16 + l15;
      if (vrole) {
        long h = (col - 512) >> 6, d = col & 63;
        long row0 = bm + wm + i * 16 + q4 * 4;
        long b = row0 >> 10, m0 = row0 & 1023;
        unsigned long long pk = (unsigned long long)bfbits(acc[i][j][0])
                              | ((unsigned long long)bfbits(acc[i][j][1]) << 16)
                              | ((unsigned long long)bfbits(acc[i][j][2]) << 32)
                              | ((unsigned long long)bfbits(acc[i][j][3]) << 48);
        *(unsigned long long*)(Vt + ((b * 8 + h) * 64 + d) * 1024 + m0) = pk;
      } else {
        long h = col >> 6, d = col & 63;
#pragma unroll
        for (int r = 0; r < 4; ++r) {
          long row = bm + wm + i * 16 + q4 * 4 + r;
          long b = row >> 10, n = row & 1023;
          float v = acc[i][j][r];
          if (role == 0) Qb[((b * 8 + h) * 1024 + n) * 64 + d] = bfbits(v * QSCALE);
          else           Kb[((b * 8 + h) * 1024 + n) * 64 + d] = bfbits(v);
        }
      }
    }
  }
}

// ---------------- flash attention: 128 q/block, 8 waves x 16 q, 2-tile supersteps ----------------
// grid 512 (2 blocks/CU, 16 waves/CU), 512 threads. K/V quad-buffered as ping-pong PAIRS:
// superstep s stages pair p^1 (tiles 2s+2, 2s+3), computes both tiles of pair p, ONE barrier.
__global__ __launch_bounds__(512)
void attn_kernel(const unsigned short* __restrict__ Qb,  // [64][1024][64] (pre-scaled)
                 const unsigned short* __restrict__ Kb,  // [64][1024][64]
                 const unsigned short* __restrict__ Vt,  // [64][64][1024]
                 unsigned short* __restrict__ Ob)        // [8192][512]
{
  __shared__ unsigned short Ksm[2][2][4096];  // [pair][tile][64 kv][64 d], 16B-chunk XOR swizzle
  __shared__ unsigned short Vsm[2][2][4096];  // [pair][tile][64 d][64 m]
  __shared__ unsigned short Psm[128 * 64];    // [128 q][64 kv], wave-private 16-row bands

  const int tid = threadIdx.x;
  const int wave = tid >> 6;
  const int lane = tid & 63;
  const int l15 = lane & 15;
  const int q4 = lane >> 4;
  const int bid = blockIdx.x;
  const int lin = (bid & 7) * 64 + (bid >> 3);  // bijective XCD chunk remap (512 % 8 == 0)
  const int bh = lin >> 3;
  const int nb = lin & 7;

  const long qrow0 = (long)bh * 1024 + nb * 128 + wave * 16;

  // Q B-frags: B[n=l15 (qrow)][k=q4*8+j (d)]
  bf16x8 qf[2];
#pragma unroll
  for (int ks = 0; ks < 2; ++ks)
    qf[ks] = *(const bf16x8*)(Qb + (qrow0 + l15) * 64 + ks * 32 + q4 * 8);

  floatx4 acc[4];
#pragma unroll
  for (int d = 0; d < 4; ++d) { acc[d][0]=0.f; acc[d][1]=0.f; acc[d][2]=0.f; acc[d][3]=0.f; }
  float suml = 0.0f;

  const unsigned short* Kbase = Kb + (long)bh * 65536;
  const unsigned short* Vbase = Vt + (long)bh * 65536;
  // staging: one 16B chunk per thread per matrix (512 threads x 16B = 8KB tile)
  const int jrow = tid >> 3;
  const int cact = (tid & 7) ^ (jrow & 7);
  const int koff = jrow * 64 + cact * 8;
  const int voff = jrow * 1024 + cact * 8;
  const int myl = tid * 16;

  // tile-invariant LDS element offsets
  const int s7 = l15 & 7;
  int kfo[2][4];   // K/V fragment reads: [(x*16+l15)*64 + (((ks*4+q4)^s7)*8)]
  int pao[2];      // P A-frag reads
  int pwo[4];      // P writes
#pragma unroll
  for (int ks = 0; ks < 2; ++ks) {
#pragma unroll
    for (int jn = 0; jn < 4; ++jn)
      kfo[ks][jn] = (jn * 16 + l15) * 64 + (((ks * 4 + q4) ^ s7) * 8);
    pao[ks] = (wave * 16 + l15) * 64 + (((ks * 4 + q4) ^ s7) * 8);
  }
#pragma unroll
  for (int jn = 0; jn < 4; ++jn)
    pwo[jn] = (wave * 16 + l15) * 64 + (((jn * 2 + (q4 >> 1)) ^ s7) * 8) + (q4 & 1) * 4;

  // prologue: stage tiles 0,1 into pair 0
  gl2lds16(Kbase + koff, (char*)Ksm[0][0] + myl);
  gl2lds16(Vbase + voff, (char*)Vsm[0][0] + myl);
  gl2lds16(Kbase + 4096 + koff, (char*)Ksm[0][1] + myl);
  gl2lds16(Vbase + 64 + voff, (char*)Vsm[0][1] + myl);
  __syncthreads();

#define ATTN_CHAIN(P, W)                                                                     \
  {                                                                                          \
    floatx4 st[4];                                                                           \
    _Pragma("unroll")                                                                        \
    for (int jn = 0; jn < 4; ++jn) {                                                         \
      st[jn][0] = 0.f; st[jn][1] = 0.f; st[jn][2] = 0.f; st[jn][3] = 0.f;                    \
    }                                                                                        \
    _Pragma("unroll")                                                                        \
    for (int ks = 0; ks < 2; ++ks) {                                                         \
      bf16x8 kfr[4];                                                                         \
      _Pragma("unroll")                                                                      \
      for (int jn = 0; jn < 4; ++jn)                                                         \
        kfr[jn] = *(const bf16x8*)(Ksm[(P)][(W)] + kfo[ks][jn]);                             \
      __builtin_amdgcn_s_setprio(1);                                                         \
      _Pragma("unroll")                                                                      \
      for (int jn = 0; jn < 4; ++jn)                                                         \
        st[jn] = __builtin_amdgcn_mfma_f32_16x16x32_bf16(kfr[jn], qf[ks], st[jn], 0, 0, 0);  \
      __builtin_amdgcn_s_setprio(0);                                                         \
    }                                                                                        \
    bf16x8 vbt[2][4]; /* V frags early: latency hides under the exp/pack VALU burst */       \
    _Pragma("unroll")                                                                        \
    for (int ks = 0; ks < 2; ++ks)                                                           \
      _Pragma("unroll")                                                                      \
      for (int dn = 0; dn < 4; ++dn)                                                         \
        vbt[ks][dn] = *(const bf16x8*)(Vsm[(P)][(W)] + kfo[ks][dn]);                         \
    _Pragma("unroll")                                                                        \
    for (int jn = 0; jn < 4; ++jn) {                                                         \
      float p0 = fast_exp2(st[jn][0]);                                                       \
      float p1 = fast_exp2(st[jn][1]);                                                       \
      float p2 = fast_exp2(st[jn][2]);                                                       \
      float p3 = fast_exp2(st[jn][3]);                                                       \
      suml += (p0 + p1) + (p2 + p3);                                                         \
      unsigned int lo = (unsigned int)bfbits(p0) | ((unsigned int)bfbits(p1) << 16);         \
      unsigned int hi = (unsigned int)bfbits(p2) | ((unsigned int)bfbits(p3) << 16);         \
      unsigned long long pk = (unsigned long long)lo | ((unsigned long long)hi << 32);       \
      *(unsigned long long*)(Psm + pwo[jn]) = pk;                                            \
    }                                                                                        \
    __asm__ volatile("s_waitcnt lgkmcnt(0)" ::: "memory");                                   \
    _Pragma("unroll")                                                                        \
    for (int ks = 0; ks < 2; ++ks) {                                                         \
      bf16x8 pa = *(const bf16x8*)(Psm + pao[ks]);                                           \
      __builtin_amdgcn_s_setprio(1);                                                         \
      _Pragma("unroll")                                                                      \
      for (int dn = 0; dn < 4; ++dn)                                                         \
        acc[dn] = __builtin_amdgcn_mfma_f32_16x16x32_bf16(pa, vbt[ks][dn], acc[dn], 0, 0, 0);\
      __builtin_amdgcn_s_setprio(0);                                                         \
    }                                                                                        \
  }

#define ATTN_SUPER(S, P, STG)                                                                \
  {                                                                                          \
    if (STG) {                                                                               \
      gl2lds16(Kbase + (2 * (S) + 2) * 4096 + koff, (char*)Ksm[(P) ^ 1][0] + myl);           \
      gl2lds16(Vbase + (2 * (S) + 2) * 64 + voff, (char*)Vsm[(P) ^ 1][0] + myl);             \
      gl2lds16(Kbase + (2 * (S) + 3) * 4096 + koff, (char*)Ksm[(P) ^ 1][1] + myl);           \
      gl2lds16(Vbase + (2 * (S) + 3) * 64 + voff, (char*)Vsm[(P) ^ 1][1] + myl);             \
    }                                                                                        \
    ATTN_CHAIN(P, 0);                                                                        \
    ATTN_CHAIN(P, 1);                                                                        \
    if ((S) < 7) __syncthreads();                                                            \
  }

  for (int ss = 0; ss < 4; ++ss) {
    ATTN_SUPER(2 * ss, 0, true);
    ATTN_SUPER(2 * ss + 1, 1, (ss < 3));
  }
#undef ATTN_SUPER
#undef ATTN_CHAIN

  // row sums: lanes l15, l15+16, l15+32, l15+48 hold partials for q=l15
  float l = suml;
  l += __shfl_xor(l, 16, 64);
  l += __shfl_xor(l, 32, 64);
  float inv = 1.0f / l;
  float invr[4];
#pragma unroll
  for (int r = 0; r < 4; ++r) invr[r] = __shfl(inv, q4 * 4 + r, 64);

  const int b = bh >> 3, h = bh & 7;
#pragma unroll
  for (int dn = 0; dn < 4; ++dn) {
#pragma unroll
    for (int r = 0; r < 4; ++r) {
      long row = (long)b * 1024 + nb * 128 + wave * 16 + q4 * 4 + r;
      long col = h * 64 + dn * 16 + l15;
      Ob[row * 512 + col] = bfbits(acc[dn][r] * invr[r]);
    }
  }
}

// ---------------- final GEMM: out = Ob * WoT^T + bias, fp32 out, 64x64x64, LDS dbuf ----------------
// BK=64: 8 steps, 8 MFMA/step, 8 barriers (was 16). 32KB LDS -> 4 blocks/CU. 1024 blocks.
__global__ __launch_bounds__(256)
void out_gemm(const unsigned short* __restrict__ A,   // Ob [8192][512]
              const unsigned short* __restrict__ Bt,  // WoT [512][512]
              float* __restrict__ outF, const float* __restrict__ bias) {
  __shared__ unsigned short As[2][64 * 64];  // 8 KB each
  __shared__ unsigned short Bs[2][64 * 64];

  int bid = blockIdx.x;
  int swz = (bid & 7) * 128 + (bid >> 3);  // bijective XCD swizzle (1024 % 8 == 0)
  const long bm = (long)(swz >> 3) * 64;
  const long bn = (long)(swz & 7) * 64;

  const int tid = threadIdx.x;
  const int wave = tid >> 6;
  const int lane = tid & 63;
  const int l15 = lane & 15;
  const int q4 = lane >> 4;
  const int s7 = l15 & 7;
  const int wm = (wave & 1) * 32;
  const int wn = (wave >> 1) * 32;
  const int K = 512, N = 512;

  // staging: 2 chunks per thread per matrix (64 rows x 8 chunks = 512 chunks)
  int aoff[2], boff[2], lds16[2];
#pragma unroll
  for (int cc = 0; cc < 2; ++cc) {
    int c = cc * 256 + tid;
    int r = c >> 3, kc = c & 7;
    int gc = kc ^ (r & 7);
    aoff[cc] = (int)(bm + r) * K + gc * 8;
    boff[cc] = (int)(bn + r) * K + gc * 8;
    lds16[cc] = c * 16;
  }
  int csw[2];
#pragma unroll
  for (int ks = 0; ks < 2; ++ks) csw[ks] = ((ks * 4 + q4) ^ s7) * 8;
  int arow[2], brow[2];
#pragma unroll
  for (int i = 0; i < 2; ++i) {
    arow[i] = (wm + i * 16 + l15) * 64;
    brow[i] = (wn + i * 16 + l15) * 64;
  }

  floatx4 acc[2][2];
#pragma unroll
  for (int i = 0; i < 2; ++i)
#pragma unroll
    for (int j = 0; j < 2; ++j) { acc[i][j][0]=0.f; acc[i][j][1]=0.f; acc[i][j][2]=0.f; acc[i][j][3]=0.f; }

#define OUT_STAGE(BUF, KOFF)                                        \
  {                                                                 \
    _Pragma("unroll")                                               \
    for (int cc = 0; cc < 2; ++cc) {                                \
      gl2lds16(A + aoff[cc] + (KOFF), (char*)As[(BUF)] + lds16[cc]);\
      gl2lds16(Bt + boff[cc] + (KOFF), (char*)Bs[(BUF)] + lds16[cc]);\
    }                                                               \
  }

#define OUT_STEP(T, CUR, DO_STAGE)                                  \
  {                                                                 \
    if (DO_STAGE) OUT_STAGE((CUR) ^ 1, ((T) + 1) * 64);             \
    _Pragma("unroll")                                               \
    for (int ks = 0; ks < 2; ++ks) {                                \
      bf16x8 af[2], bfr[2];                                         \
      _Pragma("unroll")                                             \
      for (int i = 0; i < 2; ++i) af[i] = *(const bf16x8*)(As[(CUR)] + arow[i] + csw[ks]); \
      _Pragma("unroll")                                             \
      for (int j = 0; j < 2; ++j) bfr[j] = *(const bf16x8*)(Bs[(CUR)] + brow[j] + csw[ks]); \
      _Pragma("unroll")                                             \
      for (int i = 0; i < 2; ++i)                                   \
        _Pragma("unroll")                                           \
        for (int j = 0; j < 2; ++j)                                 \
          acc[i][j] = __builtin_amdgcn_mfma_f32_16x16x32_bf16(af[i], bfr[j], acc[i][j], 0, 0, 0); \
    }                                                               \
    if ((T) < 7) __syncthreads();                                   \
  }

  OUT_STAGE(0, 0);
  __syncthreads();
  for (int tt = 0; tt < 4; ++tt) {
    OUT_STEP(2 * tt, 0, true);
    OUT_STEP(2 * tt + 1, 1, (tt < 3));
  }
#undef OUT_STEP
#undef OUT_STAGE

#pragma unroll
  for (int i = 0; i < 2; ++i) {
#pragma unroll
    for (int j = 0; j < 2; ++j) {
      long col = bn + wn + j * 16 + l15;
      float bv = bias[col];
#pragma unroll
      for (int rr = 0; rr < 4; ++rr) {
        long row = bm + wm + i * 16 + q4 * 4 + rr;
        outF[row * (long)N + col] = acc[i][j][rr] + bv;
      }
    }
  }
}

extern "C" void kernel_launch(void* const* d_in, const int* in_sizes, int n_in,
                              void* d_out, int out_size, void* d_ws, size_t ws_size,
                              hipStream_t stream) {
  const float* x   = (const float*)d_in[0];   // [8,1024,512]
  const float* ctx = (const float*)d_in[1];   // [8,1024,512]
  const float* Wq  = (const float*)d_in[2];   // [512,512]
  const float* Wkv = (const float*)d_in[3];   // [512,1024]
  const float* Wo  = (const float*)d_in[4];   // [512,512]
  const float* bo  = (const float*)d_in[5];   // [512]
  float* out = (float*)d_out;

  char* ws = (char*)d_ws;
  unsigned short* WqT  = (unsigned short*)(ws + (16u << 20));   // 0.5 MB
  unsigned short* WkvT = (unsigned short*)(ws + (17u << 20));   // 1 MB
  unsigned short* WoT  = (unsigned short*)(ws + (19u << 20));   // 0.5 MB
  unsigned short* Qb   = (unsigned short*)(ws + (20u << 20));   // 8 MB
  unsigned short* Kb   = (unsigned short*)(ws + (28u << 20));   // 8 MB
  unsigned short* Vt   = (unsigned short*)(ws + (36u << 20));   // 8 MB
  unsigned short* Ob   = (unsigned short*)(ws + (44u << 20));   // 8 MB  (total 52 MB)

  prep_kernel<<<1024, 256, 0, stream>>>(Wq, Wkv, Wo, WqT, WkvT, WoT);
  proj_gemm<<<768, 256, 0, stream>>>(x, ctx, WqT, WkvT, Qb, Kb, Vt);
  attn_kernel<<<512, 512, 0, stream>>>(Qb, Kb, Vt, Ob);
  out_gemm<<<1024, 256, 0, stream>>>(Ob, WoT, out, bo);
}

// Round 13
// 150.568 us; speedup vs baseline: 1.1045x; 1.1045x over previous
//
#include <hip/hip_runtime.h>
#include <stdint.h>

#define LOG2E 1.44269504088896340736f
#define QSCALE (0.125f * LOG2E)   // dim_head^-0.5 folded with log2(e) for exp2-domain softmax

typedef __bf16 bf16x8 __attribute__((ext_vector_type(8)));
typedef float floatx4 __attribute__((ext_vector_type(4)));

__device__ __forceinline__ unsigned short bfbits(float f) {
  __bf16 h = (__bf16)f;
  return __builtin_bit_cast(unsigned short, h);
}

__device__ __forceinline__ float fast_exp2(float x) {
#if __has_builtin(__builtin_amdgcn_exp2f)
  return __builtin_amdgcn_exp2f(x);
#else
  return exp2f(x);
#endif
}

__device__ __forceinline__ void gl2lds16(const void* g, void* l) {
  __builtin_amdgcn_global_load_lds((const __attribute__((address_space(1))) void*)g,
                                   (__attribute__((address_space(3))) void*)l, 16, 0, 0);
}

// ---------------- prep: fp32->bf16 cvt of x/ctx + transpose-cvt of Wq/Wkv/Wo ----------------
__global__ __launch_bounds__(256)
void prep_kernel(const float* __restrict__ x, const float* __restrict__ ctx,
                 const float* __restrict__ Wq, const float* __restrict__ Wkv,
                 const float* __restrict__ Wo,
                 unsigned short* __restrict__ Xb, unsigned short* __restrict__ Cb,
                 unsigned short* __restrict__ WqT, unsigned short* __restrict__ WkvT,
                 unsigned short* __restrict__ WoT) {
  int blk = blockIdx.x;
  int tid = threadIdx.x;
  if (blk < 8192) {
    const float* in = blk < 4096 ? x : ctx;
    unsigned short* out = blk < 4096 ? Xb : Cb;
    int i = (((blk & 4095) * 256) + tid) * 4;
    float4 v = *(const float4*)(in + i);
    unsigned long long pk = (unsigned long long)bfbits(v.x)
                          | ((unsigned long long)bfbits(v.y) << 16)
                          | ((unsigned long long)bfbits(v.z) << 32)
                          | ((unsigned long long)bfbits(v.w) << 48);
    *(unsigned long long*)(out + i) = pk;
  } else {
    __shared__ float tile[32][33];
    int t = blk - 8192;  // 0..1023
    const float* in; unsigned short* out; int N; int tb;
    if (t < 256)      { in = Wq;  out = WqT;  N = 512;  tb = t; }
    else if (t < 768) { in = Wkv; out = WkvT; N = 1024; tb = t - 256; }
    else              { in = Wo;  out = WoT;  N = 512;  tb = t - 768; }
    const int K = 512;
    int nbx = N / 32;
    int n0 = (tb % nbx) * 32, k0 = (tb / nbx) * 32;
    int tx = tid & 31, ty = tid >> 5;
#pragma unroll
    for (int r = ty; r < 32; r += 8)
      tile[r][tx] = in[(long)(k0 + r) * N + n0 + tx];
    __syncthreads();
#pragma unroll
    for (int r = ty; r < 32; r += 8)
      out[(long)(n0 + r) * K + k0 + tx] = bfbits(tile[tx][r]);
  }
}

// ---------------- proj: fused Q-proj and KV-proj GEMMs, 128x128x64 tiles ----------------
__global__ __launch_bounds__(256)
void proj_gemm(const unsigned short* __restrict__ Xb, const unsigned short* __restrict__ Cb,
               const unsigned short* __restrict__ WqT, const unsigned short* __restrict__ WkvT,
               unsigned short* __restrict__ Qb, unsigned short* __restrict__ Kb,
               unsigned short* __restrict__ Vt) {
  __shared__ unsigned short As[128 * 64];  // 16 KB
  __shared__ unsigned short Bs[128 * 64];  // 16 KB

  int idx0 = blockIdx.x;
  int idx = (idx0 & 7) * 96 + (idx0 >> 3);  // bijective XCD swizzle (768 % 8 == 0)
  const unsigned short* A; const unsigned short* Bt;
  long bm, bn; int role;
  if (idx < 256) { role = 0; A = Xb; Bt = WqT;  bn = (long)(idx & 3) * 128; bm = (long)(idx >> 2) * 128; }
  else { int j = idx - 256; role = 1; A = Cb; Bt = WkvT; bn = (long)(j & 7) * 128; bm = (long)(j >> 3) * 128; }

  const int tid = threadIdx.x;
  const int wave = tid >> 6;
  const int lane = tid & 63;
  const int l15 = lane & 15;
  const int q4 = lane >> 4;
  const int s7 = l15 & 7;
  const int wm = (wave & 1) * 64;
  const int wn = (wave >> 1) * 64;
  const int K = 512;

  int aoff[4], boff[4], lds16[4];
#pragma unroll
  for (int cc = 0; cc < 4; ++cc) {
    int c = cc * 256 + tid;
    int r = c >> 3, kc = c & 7;
    int sw = (kc ^ (r & 7)) * 8;
    aoff[cc] = (int)(bm + r) * K + sw;
    boff[cc] = (int)(bn + r) * K + sw;
    lds16[cc] = c * 16;
  }
  int arow[4], brow[4], csw[2];
#pragma unroll
  for (int i = 0; i < 4; ++i) {
    arow[i] = (wm + i * 16 + l15) * 64;
    brow[i] = (wn + i * 16 + l15) * 64;
  }
#pragma unroll
  for (int ks = 0; ks < 2; ++ks) csw[ks] = ((ks * 4 + q4) ^ s7) * 8;

  floatx4 acc[4][4];
#pragma unroll
  for (int i = 0; i < 4; ++i)
#pragma unroll
    for (int j = 0; j < 4; ++j) { acc[i][j][0]=0.f; acc[i][j][1]=0.f; acc[i][j][2]=0.f; acc[i][j][3]=0.f; }

  for (int k0 = 0; k0 < K; k0 += 64) {
#pragma unroll
    for (int cc = 0; cc < 4; ++cc) {
      gl2lds16(A + aoff[cc] + k0, (char*)As + lds16[cc]);
      gl2lds16(Bt + boff[cc] + k0, (char*)Bs + lds16[cc]);
    }
    __syncthreads();
#pragma unroll
    for (int ks = 0; ks < 2; ++ks) {
      bf16x8 af[4], bfr[4];
#pragma unroll
      for (int i = 0; i < 4; ++i) af[i] = *(const bf16x8*)(As + arow[i] + csw[ks]);
#pragma unroll
      for (int j = 0; j < 4; ++j) bfr[j] = *(const bf16x8*)(Bs + brow[j] + csw[ks]);
#pragma unroll
      for (int i = 0; i < 4; ++i)
#pragma unroll
        for (int j = 0; j < 4; ++j)
          acc[i][j] = __builtin_amdgcn_mfma_f32_16x16x32_bf16(af[i], bfr[j], acc[i][j], 0, 0, 0);
    }
    __syncthreads();
  }

  const bool vrole = (role == 1) && (bn >= 512);
#pragma unroll
  for (int i = 0; i < 4; ++i) {
#pragma unroll
    for (int j = 0; j < 4; ++j) {
      long col = bn + wn + j * 16 + l15;
      if (vrole) {
        long h = (col - 512) >> 6, d = col & 63;
        long row0 = bm + wm + i * 16 + q4 * 4;
        long b = row0 >> 10, m0 = row0 & 1023;
        unsigned long long pk = (unsigned long long)bfbits(acc[i][j][0])
                              | ((unsigned long long)bfbits(acc[i][j][1]) << 16)
                              | ((unsigned long long)bfbits(acc[i][j][2]) << 32)
                              | ((unsigned long long)bfbits(acc[i][j][3]) << 48);
        *(unsigned long long*)(Vt + ((b * 8 + h) * 64 + d) * 1024 + m0) = pk;
      } else {
        long h = col >> 6, d = col & 63;
#pragma unroll
        for (int r = 0; r < 4; ++r) {
          long row = bm + wm + i * 16 + q4 * 4 + r;
          long b = row >> 10, n = row & 1023;
          float v = acc[i][j][r];
          if (role == 0) Qb[((b * 8 + h) * 1024 + n) * 64 + d] = bfbits(v * QSCALE);
          else           Kb[((b * 8 + h) * 1024 + n) * 64 + d] = bfbits(v);
        }
      }
    }
  }
}

// ---------------- flash attention: 128 q/block, 8 waves x 16 q, S^T softmax ----------------
// grid 512 (2 blocks/CU, 16 waves/CU = 4/SIMD), 512 threads. KV tiles of 64, double-buffered.
// 128q/block amortizes the per-tile staging (8KB K + 8KB V, one 16B/thread round) over 2x the
// MFMA work of the failed 64q config; 8 waves give the SIMDs 4 contexts to overlap the serial
// QK->exp->pack->drain->PV chain. LDS 48KB.
__global__ __launch_bounds__(512)
void attn_kernel(const unsigned short* __restrict__ Qb,  // [64][1024][64] (pre-scaled)
                 const unsigned short* __restrict__ Kb,  // [64][1024][64]
                 const unsigned short* __restrict__ Vt,  // [64][64][1024]
                 unsigned short* __restrict__ Ob)        // [8192][512]
{
  __shared__ unsigned short Ksm[2][4096];  // [64 kv][64 d], 16B-chunk XOR swizzle
  __shared__ unsigned short Vsm[2][4096];  // [64 d][64 m], 16B-chunk XOR swizzle
  __shared__ unsigned short Psm[128 * 64]; // [128 q][64 kv], wave-private 16-row bands

  const int tid = threadIdx.x;
  const int wave = tid >> 6;
  const int lane = tid & 63;
  const int l15 = lane & 15;
  const int q4 = lane >> 4;
  const int bid = blockIdx.x;
  const int lin = (bid & 7) * 64 + (bid >> 3);  // bijective XCD chunk remap (512 % 8 == 0)
  const int bh = lin >> 3;
  const int nb = lin & 7;

  const long qrow0 = (long)bh * 1024 + nb * 128 + wave * 16;

  // Q B-frags: B[n=l15 (qrow)][k=q4*8+j (d)]
  bf16x8 qf[2];
#pragma unroll
  for (int ks = 0; ks < 2; ++ks)
    qf[ks] = *(const bf16x8*)(Qb + (qrow0 + l15) * 64 + ks * 32 + q4 * 8);

  floatx4 acc[4];
#pragma unroll
  for (int d = 0; d < 4; ++d) { acc[d][0]=0.f; acc[d][1]=0.f; acc[d][2]=0.f; acc[d][3]=0.f; }
  float suml = 0.0f;

  const unsigned short* Kbase = Kb + (long)bh * 65536;
  const unsigned short* Vbase = Vt + (long)bh * 65536;
  // staging: one 16B chunk per thread per matrix (512 threads x 16B = 8KB tile)
  const int jrow = tid >> 3;
  const int cact = (tid & 7) ^ (jrow & 7);
  const int koff = jrow * 64 + cact * 8;
  const int voff = jrow * 1024 + cact * 8;
  const int myl = tid * 16;

  // tile-invariant LDS element offsets
  const int s7 = l15 & 7;
  int kfo[2][4];   // K/V fragment reads: [(x*16+l15)*64 + (((ks*4+q4)^s7)*8)]
  int pao[2];      // P A-frag reads
  int pwo[4];      // P writes
#pragma unroll
  for (int ks = 0; ks < 2; ++ks) {
#pragma unroll
    for (int jn = 0; jn < 4; ++jn)
      kfo[ks][jn] = (jn * 16 + l15) * 64 + (((ks * 4 + q4) ^ s7) * 8);
    pao[ks] = (wave * 16 + l15) * 64 + (((ks * 4 + q4) ^ s7) * 8);
  }
#pragma unroll
  for (int jn = 0; jn < 4; ++jn)
    pwo[jn] = (wave * 16 + l15) * 64 + (((jn * 2 + (q4 >> 1)) ^ s7) * 8) + (q4 & 1) * 4;

  gl2lds16(Kbase + koff, (char*)Ksm[0] + myl);
  gl2lds16(Vbase + voff, (char*)Vsm[0] + myl);

#define ATTN_TILE(TIDX, CUR, STAGE)                                                          \
  {                                                                                          \
    __syncthreads();                                                                         \
    if (STAGE) {                                                                             \
      gl2lds16(Kbase + ((TIDX) + 1) * 4096 + koff, (char*)Ksm[(CUR) ^ 1] + myl);             \
      gl2lds16(Vbase + ((TIDX) + 1) * 64 + voff, (char*)Vsm[(CUR) ^ 1] + myl);               \
    }                                                                                        \
    floatx4 st[4];                                                                           \
    _Pragma("unroll")                                                                        \
    for (int jn = 0; jn < 4; ++jn) {                                                         \
      st[jn][0] = 0.f; st[jn][1] = 0.f; st[jn][2] = 0.f; st[jn][3] = 0.f;                    \
    }                                                                                        \
    _Pragma("unroll")                                                                        \
    for (int ks = 0; ks < 2; ++ks) {                                                         \
      bf16x8 kfr[4];                                                                         \
      _Pragma("unroll")                                                                      \
      for (int jn = 0; jn < 4; ++jn)                                                         \
        kfr[jn] = *(const bf16x8*)(Ksm[(CUR)] + kfo[ks][jn]);                                \
      __builtin_amdgcn_s_setprio(1);                                                         \
      _Pragma("unroll")                                                                      \
      for (int jn = 0; jn < 4; ++jn)                                                         \
        st[jn] = __builtin_amdgcn_mfma_f32_16x16x32_bf16(kfr[jn], qf[ks], st[jn], 0, 0, 0);  \
      __builtin_amdgcn_s_setprio(0);                                                         \
    }                                                                                        \
    bf16x8 vbt[2][4]; /* V frags early: latency hides under the exp/pack VALU burst */       \
    _Pragma("unroll")                                                                        \
    for (int ks = 0; ks < 2; ++ks)                                                           \
      _Pragma("unroll")                                                                      \
      for (int dn = 0; dn < 4; ++dn)                                                         \
        vbt[ks][dn] = *(const bf16x8*)(Vsm[(CUR)] + kfo[ks][dn]);                            \
    _Pragma("unroll")                                                                        \
    for (int jn = 0; jn < 4; ++jn) {                                                         \
      float p0 = fast_exp2(st[jn][0]);                                                       \
      float p1 = fast_exp2(st[jn][1]);                                                       \
      float p2 = fast_exp2(st[jn][2]);                                                       \
      float p3 = fast_exp2(st[jn][3]);                                                       \
      suml += (p0 + p1) + (p2 + p3);                                                         \
      unsigned int lo = (unsigned int)bfbits(p0) | ((unsigned int)bfbits(p1) << 16);         \
      unsigned int hi = (unsigned int)bfbits(p2) | ((unsigned int)bfbits(p3) << 16);         \
      unsigned long long pk = (unsigned long long)lo | ((unsigned long long)hi << 32);       \
      *(unsigned long long*)(Psm + pwo[jn]) = pk;                                            \
    }                                                                                        \
    __asm__ volatile("s_waitcnt lgkmcnt(0)" ::: "memory");                                   \
    _Pragma("unroll")                                                                        \
    for (int ks = 0; ks < 2; ++ks) {                                                         \
      bf16x8 pa = *(const bf16x8*)(Psm + pao[ks]);                                           \
      __builtin_amdgcn_s_setprio(1);                                                         \
      _Pragma("unroll")                                                                      \
      for (int dn = 0; dn < 4; ++dn)                                                         \
        acc[dn] = __builtin_amdgcn_mfma_f32_16x16x32_bf16(pa, vbt[ks][dn], acc[dn], 0, 0, 0);\
      __builtin_amdgcn_s_setprio(0);                                                         \
    }                                                                                        \
  }

  for (int tt = 0; tt < 8; ++tt) {
    ATTN_TILE(2 * tt, 0, true);
    ATTN_TILE(2 * tt + 1, 1, (tt < 7));
  }
#undef ATTN_TILE

  // row sums: lanes l15, l15+16, l15+32, l15+48 hold partials for q=l15
  float l = suml;
  l += __shfl_xor(l, 16, 64);
  l += __shfl_xor(l, 32, 64);
  float inv = 1.0f / l;
  float invr[4];
#pragma unroll
  for (int r = 0; r < 4; ++r) invr[r] = __shfl(inv, q4 * 4 + r, 64);

  const int b = bh >> 3, h = bh & 7;
#pragma unroll
  for (int dn = 0; dn < 4; ++dn) {
#pragma unroll
    for (int r = 0; r < 4; ++r) {
      long row = (long)b * 1024 + nb * 128 + wave * 16 + q4 * 4 + r;
      long col = h * 64 + dn * 16 + l15;
      Ob[row * 512 + col] = bfbits(acc[dn][r] * invr[r]);
    }
  }
}

// ---------------- final GEMM: out = Ob * WoT^T + bias, fp32 out, 64x64x64 ----------------
// 1024 blocks (4/CU, 16 waves/CU), 16KB LDS, XCD-chunked remap for A-panel L2 reuse.
__global__ __launch_bounds__(256)
void out_gemm(const unsigned short* __restrict__ A,   // Ob [8192][512]
              const unsigned short* __restrict__ Bt,  // WoT [512][512]
              float* __restrict__ outF, const float* __restrict__ bias) {
  __shared__ unsigned short As[64 * 64];   // 8 KB
  __shared__ unsigned short Bs[64 * 64];   // 8 KB

  int bid = blockIdx.x;
  int swz = (bid & 7) * 128 + (bid >> 3);  // bijective XCD swizzle (1024 % 8 == 0)
  const long bm = (long)(swz >> 3) * 64;
  const long bn = (long)(swz & 7) * 64;

  const int tid = threadIdx.x;
  const int wave = tid >> 6;
  const int lane = tid & 63;
  const int l15 = lane & 15;
  const int q4 = lane >> 4;
  const int s7 = l15 & 7;
  const int wm = (wave & 1) * 32;
  const int wn = (wave >> 1) * 32;
  const int K = 512, N = 512;

  int aoff[2], boff[2], lds16[2];
#pragma unroll
  for (int cc = 0; cc < 2; ++cc) {
    int c = cc * 256 + tid;
    int r = c >> 3, kc = c & 7;
    int sw = (kc ^ (r & 7)) * 8;
    aoff[cc] = (int)(bm + r) * K + sw;
    boff[cc] = (int)(bn + r) * K + sw;
    lds16[cc] = c * 16;
  }
  int arow[2], brow[2], csw[2];
#pragma unroll
  for (int i = 0; i < 2; ++i) {
    arow[i] = (wm + i * 16 + l15) * 64;
    brow[i] = (wn + i * 16 + l15) * 64;
  }
#pragma unroll
  for (int ks = 0; ks < 2; ++ks) csw[ks] = ((ks * 4 + q4) ^ s7) * 8;

  floatx4 acc[2][2];
#pragma unroll
  for (int i = 0; i < 2; ++i)
#pragma unroll
    for (int j = 0; j < 2; ++j) { acc[i][j][0]=0.f; acc[i][j][1]=0.f; acc[i][j][2]=0.f; acc[i][j][3]=0.f; }

  for (int k0 = 0; k0 < K; k0 += 64) {
#pragma unroll
    for (int cc = 0; cc < 2; ++cc) {
      gl2lds16(A + aoff[cc] + k0, (char*)As + lds16[cc]);
      gl2lds16(Bt + boff[cc] + k0, (char*)Bs + lds16[cc]);
    }
    __syncthreads();
#pragma unroll
    for (int ks = 0; ks < 2; ++ks) {
      bf16x8 af[2], bfr[2];
#pragma unroll
      for (int i = 0; i < 2; ++i) af[i] = *(const bf16x8*)(As + arow[i] + csw[ks]);
#pragma unroll
      for (int j = 0; j < 2; ++j) bfr[j] = *(const bf16x8*)(Bs + brow[j] + csw[ks]);
#pragma unroll
      for (int i = 0; i < 2; ++i)
#pragma unroll
        for (int j = 0; j < 2; ++j)
          acc[i][j] = __builtin_amdgcn_mfma_f32_16x16x32_bf16(af[i], bfr[j], acc[i][j], 0, 0, 0);
    }
    __syncthreads();
  }

#pragma unroll
  for (int i = 0; i < 2; ++i) {
#pragma unroll
    for (int j = 0; j < 2; ++j) {
      long col = bn + wn + j * 16 + l15;
      float bv = bias[col];
#pragma unroll
      for (int r = 0; r < 4; ++r) {
        long row = bm + wm + i * 16 + q4 * 4 + r;
        outF[row * (long)N + col] = acc[i][j][r] + bv;
      }
    }
  }
}

extern "C" void kernel_launch(void* const* d_in, const int* in_sizes, int n_in,
                              void* d_out, int out_size, void* d_ws, size_t ws_size,
                              hipStream_t stream) {
  const float* x   = (const float*)d_in[0];   // [8,1024,512]
  const float* ctx = (const float*)d_in[1];   // [8,1024,512]
  const float* Wq  = (const float*)d_in[2];   // [512,512]
  const float* Wkv = (const float*)d_in[3];   // [512,1024]
  const float* Wo  = (const float*)d_in[4];   // [512,512]
  const float* bo  = (const float*)d_in[5];   // [512]
  float* out = (float*)d_out;

  char* ws = (char*)d_ws;
  unsigned short* Xb   = (unsigned short*)(ws);                 // 8 MB
  unsigned short* Cb   = (unsigned short*)(ws + (8u  << 20));   // 8 MB
  unsigned short* WqT  = (unsigned short*)(ws + (16u << 20));   // 0.5 MB
  unsigned short* WkvT = (unsigned short*)(ws + (17u << 20));   // 1 MB
  unsigned short* WoT  = (unsigned short*)(ws + (19u << 20));   // 0.5 MB
  unsigned short* Qb   = (unsigned short*)(ws + (20u << 20));   // 8 MB
  unsigned short* Kb   = (unsigned short*)(ws + (28u << 20));   // 8 MB
  unsigned short* Vt   = (unsigned short*)(ws + (36u << 20));   // 8 MB
  unsigned short* Ob   = (unsigned short*)(ws + (44u << 20));   // 8 MB  (total 52 MB)

  prep_kernel<<<9216, 256, 0, stream>>>(x, ctx, Wq, Wkv, Wo, Xb, Cb, WqT, WkvT, WoT);
  proj_gemm<<<768, 256, 0, stream>>>(Xb, Cb, WqT, WkvT, Qb, Kb, Vt);
  attn_kernel<<<512, 512, 0, stream>>>(Qb, Kb, Vt, Ob);
  out_gemm<<<1024, 256, 0, stream>>>(Ob, WoT, out, bo);
}